// Round 1
// baseline (297.344 us; speedup 1.0000x reference)
//
#include <hip/hip_runtime.h>
#include <float.h>

#define NUM_Q 8192
#define NUM_P 4096

// One block (256 threads = 4 waves) per row.
// Each thread holds 16 pred values (4x float4) + relevance mask in registers.
// Phase 1: block-wide min over relevant entries.
// Phase 2: block-wide sum of relu(pred - min_rlv) over non-relevant entries.
// Pre-scaled atomicAdd into the scalar output.
__global__ __launch_bounds__(256)
void mmrl_kernel(const float* __restrict__ pred,
                 const int* __restrict__ y,
                 float* __restrict__ out) {
    const int row = blockIdx.x;
    const int t = threadIdx.x;

    const float4* prow = reinterpret_cast<const float4*>(pred + (size_t)row * NUM_P);
    const int4*   yrow = reinterpret_cast<const int4*>(y + (size_t)row * NUM_P);

    float4 pv[4];
    int4   yv[4];
#pragma unroll
    for (int i = 0; i < 4; ++i) {
        pv[i] = prow[t + 256 * i];
        yv[i] = yrow[t + 256 * i];
    }

    // ---- Phase 1: min over relevant (y == 1) ----
    float lmin = FLT_MAX;
#pragma unroll
    for (int i = 0; i < 4; ++i) {
        if (yv[i].x == 1) lmin = fminf(lmin, pv[i].x);
        if (yv[i].y == 1) lmin = fminf(lmin, pv[i].y);
        if (yv[i].z == 1) lmin = fminf(lmin, pv[i].z);
        if (yv[i].w == 1) lmin = fminf(lmin, pv[i].w);
    }
    // wave (64-lane) butterfly reduce
#pragma unroll
    for (int off = 32; off > 0; off >>= 1)
        lmin = fminf(lmin, __shfl_xor(lmin, off));

    __shared__ float smin[4];
    __shared__ float ssum[4];
    const int wave = t >> 6;
    if ((t & 63) == 0) smin[wave] = lmin;
    __syncthreads();
    const float rmin = fminf(fminf(smin[0], smin[1]), fminf(smin[2], smin[3]));

    // ---- Phase 2: sum of relu(pred - rmin) over non-relevant ----
    float lsum = 0.0f;
#pragma unroll
    for (int i = 0; i < 4; ++i) {
        if (yv[i].x != 1) lsum += fmaxf(pv[i].x - rmin, 0.0f);
        if (yv[i].y != 1) lsum += fmaxf(pv[i].y - rmin, 0.0f);
        if (yv[i].z != 1) lsum += fmaxf(pv[i].z - rmin, 0.0f);
        if (yv[i].w != 1) lsum += fmaxf(pv[i].w - rmin, 0.0f);
    }
#pragma unroll
    for (int off = 32; off > 0; off >>= 1)
        lsum += __shfl_xor(lsum, off);

    if ((t & 63) == 0) ssum[wave] = lsum;
    __syncthreads();

    if (t == 0) {
        const float total = (ssum[0] + ssum[1]) + (ssum[2] + ssum[3]);
        // mean over Q*P = 2^25 — exact power-of-two scale
        const float scale = 1.0f / ((float)NUM_Q * (float)NUM_P);
        atomicAdd(out, total * scale);
    }
}

extern "C" void kernel_launch(void* const* d_in, const int* in_sizes, int n_in,
                              void* d_out, int out_size, void* d_ws, size_t ws_size,
                              hipStream_t stream) {
    const float* pred = (const float*)d_in[0];
    const int*   y    = (const int*)d_in[1];
    float* out = (float*)d_out;

    // d_out is poisoned with 0xAA before every launch — zero it first.
    hipMemsetAsync(out, 0, sizeof(float), stream);

    mmrl_kernel<<<NUM_Q, 256, 0, stream>>>(pred, y, out);
}

// Round 2
// 268.025 us; speedup vs baseline: 1.1094x; 1.1094x over previous
//
#include <hip/hip_runtime.h>
#include <float.h>

#define NUM_Q 8192
#define NUM_P 4096

// One block (256 threads = 4 waves) per row.
// Each thread holds 16 pred values (4x float4) + relevance mask in registers.
// Phase 1: block-wide min over relevant entries.
// Phase 2: block-wide sum of relu(pred - min_rlv) over non-relevant entries.
// Per-row partial sum -> d_ws[row]; a second kernel reduces (no atomics:
// 8192 same-address atomicAdds serialized at one L3 slice in round 0).
__global__ __launch_bounds__(256)
void mmrl_kernel(const float* __restrict__ pred,
                 const int* __restrict__ y,
                 float* __restrict__ ws) {
    const int row = blockIdx.x;
    const int t = threadIdx.x;

    const float4* prow = reinterpret_cast<const float4*>(pred + (size_t)row * NUM_P);
    const int4*   yrow = reinterpret_cast<const int4*>(y + (size_t)row * NUM_P);

    float4 pv[4];
    int4   yv[4];
#pragma unroll
    for (int i = 0; i < 4; ++i) {
        pv[i] = prow[t + 256 * i];
        yv[i] = yrow[t + 256 * i];
    }

    // ---- Phase 1: min over relevant (y == 1) ----
    float lmin = FLT_MAX;
#pragma unroll
    for (int i = 0; i < 4; ++i) {
        if (yv[i].x == 1) lmin = fminf(lmin, pv[i].x);
        if (yv[i].y == 1) lmin = fminf(lmin, pv[i].y);
        if (yv[i].z == 1) lmin = fminf(lmin, pv[i].z);
        if (yv[i].w == 1) lmin = fminf(lmin, pv[i].w);
    }
    // wave (64-lane) butterfly reduce
#pragma unroll
    for (int off = 32; off > 0; off >>= 1)
        lmin = fminf(lmin, __shfl_xor(lmin, off));

    __shared__ float smin[4];
    __shared__ float ssum[4];
    const int wave = t >> 6;
    if ((t & 63) == 0) smin[wave] = lmin;
    __syncthreads();
    const float rmin = fminf(fminf(smin[0], smin[1]), fminf(smin[2], smin[3]));

    // ---- Phase 2: sum of relu(pred - rmin) over non-relevant ----
    float lsum = 0.0f;
#pragma unroll
    for (int i = 0; i < 4; ++i) {
        if (yv[i].x != 1) lsum += fmaxf(pv[i].x - rmin, 0.0f);
        if (yv[i].y != 1) lsum += fmaxf(pv[i].y - rmin, 0.0f);
        if (yv[i].z != 1) lsum += fmaxf(pv[i].z - rmin, 0.0f);
        if (yv[i].w != 1) lsum += fmaxf(pv[i].w - rmin, 0.0f);
    }
#pragma unroll
    for (int off = 32; off > 0; off >>= 1)
        lsum += __shfl_xor(lsum, off);

    if ((t & 63) == 0) ssum[wave] = lsum;
    __syncthreads();

    if (t == 0) {
        ws[row] = (ssum[0] + ssum[1]) + (ssum[2] + ssum[3]);
    }
}

// Single-block reduction over the 8192 per-row partials.
__global__ __launch_bounds__(256)
void mmrl_reduce_kernel(const float* __restrict__ partial,
                        float* __restrict__ out) {
    const int t = threadIdx.x;
    const float4* p4 = reinterpret_cast<const float4*>(partial);
    float s = 0.0f;
#pragma unroll
    for (int i = 0; i < 8; ++i) {  // 256 threads * 8 float4 = 2048 float4 = 8192 floats
        float4 v = p4[t + 256 * i];
        s += (v.x + v.y) + (v.z + v.w);
    }
#pragma unroll
    for (int off = 32; off > 0; off >>= 1)
        s += __shfl_xor(s, off);

    __shared__ float ss[4];
    if ((t & 63) == 0) ss[t >> 6] = s;
    __syncthreads();

    if (t == 0) {
        const float total = (ss[0] + ss[1]) + (ss[2] + ss[3]);
        // mean over Q*P = 2^25 — exact power-of-two scale
        out[0] = total * (1.0f / ((float)NUM_Q * (float)NUM_P));
    }
}

extern "C" void kernel_launch(void* const* d_in, const int* in_sizes, int n_in,
                              void* d_out, int out_size, void* d_ws, size_t ws_size,
                              hipStream_t stream) {
    const float* pred = (const float*)d_in[0];
    const int*   y    = (const int*)d_in[1];
    float* out = (float*)d_out;
    float* ws  = (float*)d_ws;  // 8192 floats = 32 KB of scratch

    mmrl_kernel<<<NUM_Q, 256, 0, stream>>>(pred, y, ws);
    mmrl_reduce_kernel<<<1, 256, 0, stream>>>(ws, out);
}